// Round 1
// baseline (40.651 us; speedup 1.0000x reference)
//
#include <hip/hip_runtime.h>
#include <math.h>

// f(x) = tanh-MLP(x), layers 1->16->32->32->16->3.
// Strategy: precompute f on a TN-point grid (kernel 1, into d_ws), then
// memory-bound lerp (kernel 2, table staged in LDS).

#define TN 2048
#define XLO (-10.0f)
#define XHI (10.0f)

__device__ __forceinline__ float fast_tanh(float x) {
    // tanh(x) = 1 - 2/(exp2(2x*log2e)+1); v_exp_f32 + v_rcp_f32, ~1e-6 abs err
    float t = __builtin_amdgcn_exp2f(x * 2.885390081777927f);
    return 1.0f - 2.0f * __builtin_amdgcn_rcpf(t + 1.0f);
}

__global__ __launch_bounds__(256) void build_table(
    const float* __restrict__ W0, const float* __restrict__ b0,
    const float* __restrict__ W1, const float* __restrict__ b1,
    const float* __restrict__ W2, const float* __restrict__ b2,
    const float* __restrict__ W3, const float* __restrict__ b3,
    const float* __restrict__ W4, const float* __restrict__ b4,
    float4* __restrict__ table)
{
    int i = blockIdx.x * 256 + threadIdx.x;
    if (i >= TN) return;
    const float h = (XHI - XLO) / (float)(TN - 1);
    float x = XLO + (float)i * h;

    float a[32], c[32];
    // L0: 1 -> 16
    #pragma unroll
    for (int j = 0; j < 16; ++j) a[j] = fast_tanh(fmaf(x, W0[j], b0[j]));
    // L1: 16 -> 32   (W1[k,j] = W1[k*32+j])
    #pragma unroll
    for (int j = 0; j < 32; ++j) {
        float acc = b1[j];
        #pragma unroll
        for (int k = 0; k < 16; ++k) acc = fmaf(a[k], W1[k * 32 + j], acc);
        c[j] = fast_tanh(acc);
    }
    // L2: 32 -> 32
    #pragma unroll
    for (int j = 0; j < 32; ++j) {
        float acc = b2[j];
        #pragma unroll
        for (int k = 0; k < 32; ++k) acc = fmaf(c[k], W2[k * 32 + j], acc);
        a[j] = fast_tanh(acc);
    }
    // L3: 32 -> 16
    #pragma unroll
    for (int j = 0; j < 16; ++j) {
        float acc = b3[j];
        #pragma unroll
        for (int k = 0; k < 32; ++k) acc = fmaf(a[k], W3[k * 16 + j], acc);
        c[j] = fast_tanh(acc);
    }
    // L4: 16 -> 3
    float o[3];
    #pragma unroll
    for (int j = 0; j < 3; ++j) {
        float acc = b4[j];
        #pragma unroll
        for (int k = 0; k < 16; ++k) acc = fmaf(c[k], W4[k * 3 + j], acc);
        o[j] = fast_tanh(acc);
    }
    table[i] = make_float4(o[0], o[1], o[2], 0.0f);
}

__global__ __launch_bounds__(256) void apply_table(
    const float4* __restrict__ x4, const float4* __restrict__ table_g,
    float4* __restrict__ out4, int n4)
{
    __shared__ float4 tab[TN];
    for (int i = threadIdx.x; i < TN; i += 256) tab[i] = table_g[i];
    __syncthreads();

    const float inv_h = (float)(TN - 1) / (XHI - XLO);
    int stride = gridDim.x * 256;
    for (int idx = blockIdx.x * 256 + threadIdx.x; idx < n4; idx += stride) {
        float4 xv = x4[idx];
        float xs[4] = {xv.x, xv.y, xv.z, xv.w};
        float y[12];
        #pragma unroll
        for (int c = 0; c < 4; ++c) {
            float x = fminf(fmaxf(xs[c], XLO), XHI);
            float f = (x - XLO) * inv_h;
            int i0 = (int)f;
            i0 = min(i0, TN - 2);
            float fr = f - (float)i0;
            float4 t0 = tab[i0];
            float4 t1 = tab[i0 + 1];
            y[c * 3 + 0] = fmaf(fr, t1.x - t0.x, t0.x);
            y[c * 3 + 1] = fmaf(fr, t1.y - t0.y, t0.y);
            y[c * 3 + 2] = fmaf(fr, t1.z - t0.z, t0.z);
        }
        float4* o = out4 + (size_t)idx * 3;
        o[0] = make_float4(y[0], y[1], y[2], y[3]);
        o[1] = make_float4(y[4], y[5], y[6], y[7]);
        o[2] = make_float4(y[8], y[9], y[10], y[11]);
    }
}

extern "C" void kernel_launch(void* const* d_in, const int* in_sizes, int n_in,
                              void* d_out, int out_size, void* d_ws, size_t ws_size,
                              hipStream_t stream) {
    const float* x  = (const float*)d_in[0];
    const float* W0 = (const float*)d_in[1];
    const float* b0 = (const float*)d_in[2];
    const float* W1 = (const float*)d_in[3];
    const float* b1 = (const float*)d_in[4];
    const float* W2 = (const float*)d_in[5];
    const float* b2 = (const float*)d_in[6];
    const float* W3 = (const float*)d_in[7];
    const float* b3 = (const float*)d_in[8];
    const float* W4 = (const float*)d_in[9];
    const float* b4 = (const float*)d_in[10];
    float4* table = (float4*)d_ws;   // needs TN*16 = 32 KB of scratch

    build_table<<<(TN + 255) / 256, 256, 0, stream>>>(
        W0, b0, W1, b1, W2, b2, W3, b3, W4, b4, table);

    int n  = in_sizes[0];      // 4194304 elements
    int n4 = n / 4;            // float4 chunks
    int blocks = 1024;         // 4 blocks/CU, grid-stride over n4
    apply_table<<<blocks, 256, 0, stream>>>(
        (const float4*)x, table, (float4*)d_out, n4);
}